// Round 2
// baseline (4086.633 us; speedup 1.0000x reference)
//
#include <hip/hip_runtime.h>

#define NGRAPH 100000
#define NEDGE  1600000
#define NTOT   1700000   // edges + self loops
#define HID    128

// ---------- dtype detection: int64 edge_index has all-zero odd 32-bit words ----------
__global__ void k_detect(const int* __restrict__ ei, int* __restrict__ flag) {
    int t = threadIdx.x;                       // 64 threads
    int v = ei[2 * t + 1];                     // odd words of src region
    unsigned long long b = __ballot(v != 0);
    if (t == 0) flag[0] = (b == 0ull) ? 1 : 0; // 1 => int64, 0 => int32
}

__device__ __forceinline__ int e_src(const int* ei, int is64, int e) {
    return is64 ? ei[2 * e] : ei[e];
}
__device__ __forceinline__ int e_dst(const int* ei, int is64, int e) {
    return is64 ? ei[2 * NEDGE + 2 * e] : ei[NEDGE + e];
}

// ---------- build combined features [NGRAPH][7]; init deg=1 (self loop) ----------
__global__ void k_prep(const float* __restrict__ obs,
                       float* __restrict__ comb, float* __restrict__ deg) {
    int i = blockIdx.x * blockDim.x + threadIdx.x;
    if (i >= NGRAPH) return;
    int n = i / 20, c = i % 20;
    const float* nf = obs + 3 + n * 4;
    const float* cf = obs + 3 + 20000 + c * 3;
    float* o = comb + i * 7;
    o[0] = nf[0]; o[1] = nf[1]; o[2] = nf[2]; o[3] = nf[3];
    o[4] = cf[0]; o[5] = cf[1]; o[6] = cf[2];
    deg[i] = 1.0f;
}

__global__ void k_deg(const int* __restrict__ ei, const int* __restrict__ flag,
                      float* __restrict__ deg) {
    int e = blockIdx.x * blockDim.x + threadIdx.x;
    if (e >= NEDGE) return;
    int is64 = flag[0];
    atomicAdd(&deg[e_dst(ei, is64, e)], 1.0f);
}

__global__ void k_dinv(const float* __restrict__ deg, float* __restrict__ dinv) {
    int i = blockIdx.x * blockDim.x + threadIdx.x;
    if (i >= NGRAPH) return;
    dinv[i] = rsqrtf(deg[i]);   // deg >= 1 always (self loop)
}

__global__ void k_norm(const int* __restrict__ ei, const int* __restrict__ flag,
                       const float* __restrict__ dinv, float* __restrict__ nrm) {
    int e = blockIdx.x * blockDim.x + threadIdx.x;
    if (e >= NEDGE) return;
    int is64 = flag[0];
    nrm[e] = dinv[e_src(ei, is64, e)] * dinv[e_dst(ei, is64, e)];
}

// ---------- layer-1 aggregation on 7-dim raw features (pre-matmul) ----------
__global__ void k_agg7(const int* __restrict__ ei, const int* __restrict__ flag,
                       const float* __restrict__ nrm, const float* __restrict__ dinv,
                       const float* __restrict__ comb, float* __restrict__ agg1) {
    int e = blockIdx.x * blockDim.x + threadIdx.x;
    if (e >= NTOT) return;
    int is64 = flag[0];
    int s, d; float w;
    if (e < NEDGE) {
        s = e_src(ei, is64, e);
        d = e_dst(ei, is64, e);
        w = nrm[e];
    } else {
        s = d = e - NEDGE;
        float dv = dinv[s];
        w = dv * dv;
    }
    const float* sp = comb + s * 7;
    float* dp = agg1 + d * 7;
    #pragma unroll
    for (int f = 0; f < 7; ++f) atomicAdd(&dp[f], w * sp[f]);
}

// ---------- x1 = relu(agg1 @ W1 + b1) ----------
__global__ void __launch_bounds__(128) k_l1(const float* __restrict__ agg1,
                                            const float* __restrict__ W1,
                                            const float* __restrict__ b1,
                                            float* __restrict__ x1) {
    int i = blockIdx.x;
    int h = threadIdx.x;
    float a[7];
    #pragma unroll
    for (int f = 0; f < 7; ++f) a[f] = agg1[i * 7 + f];
    float acc = b1[h];
    #pragma unroll
    for (int f = 0; f < 7; ++f) acc += a[f] * W1[f * HID + h];
    x1[i * HID + h] = fmaxf(acc, 0.0f);
}

// ---------- layer-2 aggregation on 128-dim x1 (the heavy pass) ----------
__global__ void __launch_bounds__(256) k_agg128(const int* __restrict__ ei,
                                                const int* __restrict__ flag,
                                                const float* __restrict__ nrm,
                                                const float* __restrict__ dinv,
                                                const float* __restrict__ x1,
                                                float* __restrict__ agg2) {
    long long t = (long long)blockIdx.x * blockDim.x + threadIdx.x;
    int e = (int)(t >> 5);
    int q = (int)(t & 31);
    if (e >= NTOT) return;
    int is64 = flag[0];
    int s, d; float w;
    if (e < NEDGE) {
        s = e_src(ei, is64, e);
        d = e_dst(ei, is64, e);
        w = nrm[e];
    } else {
        s = d = e - NEDGE;
        float dv = dinv[s];
        w = dv * dv;
    }
    float4 v = reinterpret_cast<const float4*>(x1 + (size_t)s * HID)[q];
    float* dp = agg2 + (size_t)d * HID + q * 4;
    atomicAdd(&dp[0], w * v.x);
    atomicAdd(&dp[1], w * v.y);
    atomicAdd(&dp[2], w * v.z);
    atomicAdd(&dp[3], w * v.w);
}

// ---------- x2 = relu(agg2 @ W2 + b2)  (8 nodes/block, 32 lanes/node, float4) ----------
__global__ void __launch_bounds__(256) k_l2(const float* __restrict__ agg2,
                                            const float* __restrict__ W2,
                                            const float* __restrict__ b2,
                                            float* __restrict__ x2) {
    int g = threadIdx.x >> 5;
    int l = threadIdx.x & 31;
    int node = blockIdx.x * 8 + g;
    int h0 = l * 4;
    const float4* arow = reinterpret_cast<const float4*>(agg2 + (size_t)node * HID);
    float4 acc = *reinterpret_cast<const float4*>(b2 + h0);
    #pragma unroll 4
    for (int f4 = 0; f4 < 32; ++f4) {
        float4 a  = arow[f4];
        float4 w0 = *reinterpret_cast<const float4*>(W2 + (f4 * 4 + 0) * HID + h0);
        float4 w1 = *reinterpret_cast<const float4*>(W2 + (f4 * 4 + 1) * HID + h0);
        float4 w2 = *reinterpret_cast<const float4*>(W2 + (f4 * 4 + 2) * HID + h0);
        float4 w3 = *reinterpret_cast<const float4*>(W2 + (f4 * 4 + 3) * HID + h0);
        acc.x += a.x * w0.x + a.y * w1.x + a.z * w2.x + a.w * w3.x;
        acc.y += a.x * w0.y + a.y * w1.y + a.z * w2.y + a.w * w3.y;
        acc.z += a.x * w0.z + a.y * w1.z + a.z * w2.z + a.w * w3.z;
        acc.w += a.x * w0.w + a.y * w1.w + a.z * w2.w + a.w * w3.w;
    }
    float4 r;
    r.x = fmaxf(acc.x, 0.0f); r.y = fmaxf(acc.y, 0.0f);
    r.z = fmaxf(acc.z, 0.0f); r.w = fmaxf(acc.w, 0.0f);
    *reinterpret_cast<float4*>(x2 + (size_t)node * HID + h0) = r;
}

// ---------- fused fc1(+relu) + fc2 ----------
__global__ void __launch_bounds__(256) k_fc(const float* __restrict__ x2,
                                            const float* __restrict__ fc1w,
                                            const float* __restrict__ fc1b,
                                            const float* __restrict__ fc2w,
                                            const float* __restrict__ fc2b,
                                            float* __restrict__ out) {
    int g = threadIdx.x >> 5;
    int l = threadIdx.x & 31;
    int node = blockIdx.x * 8 + g;
    int h0 = l * 4;
    const float4* xrow = reinterpret_cast<const float4*>(x2 + (size_t)node * HID);
    float4 acc = *reinterpret_cast<const float4*>(fc1b + h0);
    #pragma unroll 4
    for (int f4 = 0; f4 < 32; ++f4) {
        float4 a  = xrow[f4];
        float4 w0 = *reinterpret_cast<const float4*>(fc1w + (f4 * 4 + 0) * HID + h0);
        float4 w1 = *reinterpret_cast<const float4*>(fc1w + (f4 * 4 + 1) * HID + h0);
        float4 w2 = *reinterpret_cast<const float4*>(fc1w + (f4 * 4 + 2) * HID + h0);
        float4 w3 = *reinterpret_cast<const float4*>(fc1w + (f4 * 4 + 3) * HID + h0);
        acc.x += a.x * w0.x + a.y * w1.x + a.z * w2.x + a.w * w3.x;
        acc.y += a.x * w0.y + a.y * w1.y + a.z * w2.y + a.w * w3.y;
        acc.z += a.x * w0.z + a.y * w1.z + a.z * w2.z + a.w * w3.z;
        acc.w += a.x * w0.w + a.y * w1.w + a.z * w2.w + a.w * w3.w;
    }
    acc.x = fmaxf(acc.x, 0.0f); acc.y = fmaxf(acc.y, 0.0f);
    acc.z = fmaxf(acc.z, 0.0f); acc.w = fmaxf(acc.w, 0.0f);
    float4 w = *reinterpret_cast<const float4*>(fc2w + h0);
    float p = acc.x * w.x + acc.y * w.y + acc.z * w.z + acc.w * w.w;
    #pragma unroll
    for (int m = 16; m >= 1; m >>= 1) p += __shfl_xor(p, m);
    if (l == 0) out[node] = p + fc2b[0];
}

extern "C" void kernel_launch(void* const* d_in, const int* in_sizes, int n_in,
                              void* d_out, int out_size, void* d_ws, size_t ws_size,
                              hipStream_t stream) {
    const float* obs  = (const float*)d_in[0];
    const int*   ei   = (const int*)d_in[1];
    const float* W1   = (const float*)d_in[2];
    const float* b1   = (const float*)d_in[3];
    const float* W2   = (const float*)d_in[4];
    const float* b2   = (const float*)d_in[5];
    const float* fc1w = (const float*)d_in[6];
    const float* fc1b = (const float*)d_in[7];
    const float* fc2w = (const float*)d_in[8];
    const float* fc2b = (const float*)d_in[9];
    float* out = (float*)d_out;

    char* base = (char*)d_ws;
    size_t off = 0;
    auto take = [&](size_t bytes) {
        char* p = base + off;
        off += (bytes + 255) & ~(size_t)255;
        return p;
    };
    float* deg  = (float*)take((size_t)NGRAPH * 4);
    float* dinv = (float*)take((size_t)NGRAPH * 4);
    float* nrm  = (float*)take((size_t)NEDGE * 4);
    float* comb = (float*)take((size_t)NGRAPH * 7 * 4);
    float* agg1 = (float*)take((size_t)NGRAPH * 7 * 4);
    float* x1   = (float*)take((size_t)NGRAPH * HID * 4);
    float* agg2 = (float*)take((size_t)NGRAPH * HID * 4);
    int*   flag = (int*)take(256);

    // ws is re-poisoned 0xAA before every timed launch: zero the accumulators.
    hipMemsetAsync(agg1, 0, (size_t)NGRAPH * 7 * 4, stream);
    hipMemsetAsync(agg2, 0, (size_t)NGRAPH * HID * 4, stream);

    k_detect<<<1, 64, 0, stream>>>(ei, flag);
    k_prep<<<(NGRAPH + 255) / 256, 256, 0, stream>>>(obs, comb, deg);
    k_deg<<<(NEDGE + 255) / 256, 256, 0, stream>>>(ei, flag, deg);
    k_dinv<<<(NGRAPH + 255) / 256, 256, 0, stream>>>(deg, dinv);
    k_norm<<<(NEDGE + 255) / 256, 256, 0, stream>>>(ei, flag, dinv, nrm);
    k_agg7<<<(NTOT + 255) / 256, 256, 0, stream>>>(ei, flag, nrm, dinv, comb, agg1);
    k_l1<<<NGRAPH, 128, 0, stream>>>(agg1, W1, b1, x1);
    k_agg128<<<(int)(((long long)NTOT * 32) / 256), 256, 0, stream>>>(ei, flag, nrm, dinv, x1, agg2);
    k_l2<<<NGRAPH / 8, 256, 0, stream>>>(agg2, W2, b2, x1 /* reuse as x2 */);
    k_fc<<<NGRAPH / 8, 256, 0, stream>>>(x1, fc1w, fc1b, fc2w, fc2b, out);
}

// Round 5
// 912.810 us; speedup vs baseline: 4.4770x; 4.4770x over previous
//
#include <hip/hip_runtime.h>

#define NGRAPH 100000
#define NEDGE  1600000
#define HID    128
#define SCAN_B 512
#define NBLK   ((NGRAPH + SCAN_B - 1) / SCAN_B)   // 196

// ---------- dtype detection: int64 edge_index has all-zero odd 32-bit words ----------
__global__ void k_detect(const int* __restrict__ ei, int* __restrict__ flag) {
    int t = threadIdx.x;                       // 64 threads
    int v = ei[2 * t + 1];                     // odd words of src region
    unsigned long long b = __ballot(v != 0);
    if (t == 0) flag[0] = (b == 0ull) ? 1 : 0; // 1 => int64, 0 => int32
}

__device__ __forceinline__ int e_src(const int* ei, int is64, int e) {
    return is64 ? ei[2 * e] : ei[e];
}
__device__ __forceinline__ int e_dst(const int* ei, int is64, int e) {
    return is64 ? ei[2 * NEDGE + 2 * e] : ei[NEDGE + e];
}

// ---------- combined features [NGRAPH][7]; deg (edge-only) = 0; fill = 0 ----------
__global__ void k_prep(const float* __restrict__ obs,
                       float* __restrict__ comb, int* __restrict__ deg,
                       int* __restrict__ fill) {
    int i = blockIdx.x * blockDim.x + threadIdx.x;
    if (i >= NGRAPH) return;
    int n = i / 20, c = i % 20;
    const float* nf = obs + 3 + n * 4;
    const float* cf = obs + 3 + 20000 + c * 3;
    float* o = comb + i * 7;
    o[0] = nf[0]; o[1] = nf[1]; o[2] = nf[2]; o[3] = nf[3];
    o[4] = cf[0]; o[5] = cf[1]; o[6] = cf[2];
    deg[i] = 0;
    fill[i] = 0;
}

__global__ void k_deg(const int* __restrict__ ei, const int* __restrict__ flag,
                      int* __restrict__ deg) {
    int e = blockIdx.x * blockDim.x + threadIdx.x;
    if (e >= NEDGE) return;
    atomicAdd(&deg[e_dst(ei, flag[0], e)], 1);
}

__global__ void k_dinv(const int* __restrict__ deg, float* __restrict__ dinv) {
    int i = blockIdx.x * blockDim.x + threadIdx.x;
    if (i >= NGRAPH) return;
    dinv[i] = rsqrtf((float)(deg[i] + 1));     // +1: self loop
}

// ---------- exclusive scan of deg -> rowptr (3-kernel hierarchical) ----------
__global__ void __launch_bounds__(SCAN_B) k_scan1(const int* __restrict__ deg,
                                                  int* __restrict__ rowptr,
                                                  int* __restrict__ sums) {
    __shared__ int sh[SCAN_B];
    int t = threadIdx.x;
    int i = blockIdx.x * SCAN_B + t;
    int val = (i < NGRAPH) ? deg[i] : 0;
    sh[t] = val;
    __syncthreads();
    for (int o = 1; o < SCAN_B; o <<= 1) {
        int x = (t >= o) ? sh[t - o] : 0;
        __syncthreads();
        sh[t] += x;
        __syncthreads();
    }
    if (i < NGRAPH) rowptr[i] = sh[t] - val;          // exclusive within block
    if (t == SCAN_B - 1) sums[blockIdx.x] = sh[t];    // block total
}

__global__ void __launch_bounds__(256) k_scan2(int* __restrict__ sums) {
    __shared__ int sh[256];
    int t = threadIdx.x;
    int val = (t < NBLK) ? sums[t] : 0;
    sh[t] = val;
    __syncthreads();
    for (int o = 1; o < 256; o <<= 1) {
        int x = (t >= o) ? sh[t - o] : 0;
        __syncthreads();
        sh[t] += x;
        __syncthreads();
    }
    if (t < NBLK) sums[t] = sh[t] - val;              // exclusive block offsets
}

__global__ void __launch_bounds__(SCAN_B) k_scan3(int* __restrict__ rowptr,
                                                  const int* __restrict__ sums) {
    int i = blockIdx.x * SCAN_B + threadIdx.x;
    if (i < NGRAPH) rowptr[i] += sums[blockIdx.x];
}

// ---------- scatter edges into CSR slots ----------
__global__ void k_fill(const int* __restrict__ ei, const int* __restrict__ flag,
                       const float* __restrict__ dinv,
                       const int* __restrict__ rowptr, int* __restrict__ fill,
                       int* __restrict__ csr_src, float* __restrict__ csr_w) {
    int e = blockIdx.x * blockDim.x + threadIdx.x;
    if (e >= NEDGE) return;
    int is64 = flag[0];
    int s = e_src(ei, is64, e);
    int d = e_dst(ei, is64, e);
    int pos = rowptr[d] + atomicAdd(&fill[d], 1);
    csr_src[pos] = s;
    csr_w[pos] = dinv[s] * dinv[d];
}

// ---------- layer-1 agg over CSR: 8 lanes/node on 7-dim raw features ----------
__global__ void __launch_bounds__(256) k_agg7(const int* __restrict__ rowptr,
                                              const int* __restrict__ deg,
                                              const int* __restrict__ csr_src,
                                              const float* __restrict__ csr_w,
                                              const float* __restrict__ dinv,
                                              const float* __restrict__ comb,
                                              float* __restrict__ agg1) {
    int d = blockIdx.x * 32 + (threadIdx.x >> 3);
    int f = threadIdx.x & 7;
    if (f >= 7) return;
    int start = rowptr[d], n = deg[d];
    float acc = 0.0f;
    for (int j = 0; j < n; ++j) {
        int s = csr_src[start + j];
        float w = csr_w[start + j];
        acc += w * comb[s * 7 + f];
    }
    float dv = dinv[d];
    acc += dv * dv * comb[d * 7 + f];                 // self loop
    agg1[d * 7 + f] = acc;
}

// ---------- x1 = relu(agg1 @ W1 + b1) ----------
__global__ void __launch_bounds__(128) k_l1(const float* __restrict__ agg1,
                                            const float* __restrict__ W1,
                                            const float* __restrict__ b1,
                                            float* __restrict__ x1) {
    int i = blockIdx.x;
    int h = threadIdx.x;
    float a[7];
    #pragma unroll
    for (int f = 0; f < 7; ++f) a[f] = agg1[i * 7 + f];
    float acc = b1[h];
    #pragma unroll
    for (int f = 0; f < 7; ++f) acc += a[f] * W1[f * HID + h];
    x1[i * HID + h] = fmaxf(acc, 0.0f);
}

// ---------- layer-2 agg over CSR: 1 wave/node, lane holds 2 of 128 feats ----------
__global__ void __launch_bounds__(256) k_agg2(const int* __restrict__ rowptr,
                                              const int* __restrict__ deg,
                                              const int* __restrict__ csr_src,
                                              const float* __restrict__ csr_w,
                                              const float* __restrict__ dinv,
                                              const float* __restrict__ x1,
                                              float* __restrict__ agg2) {
    int wave = threadIdx.x >> 6;
    int lane = threadIdx.x & 63;
    int d = blockIdx.x * 4 + wave;
    int f0 = lane * 2;
    int start = rowptr[d], n = deg[d];
    float2 acc = {0.0f, 0.0f};
    for (int j = 0; j < n; ++j) {
        int s = csr_src[start + j];        // same addr across wave -> broadcast
        float w = csr_w[start + j];
        float2 v = *reinterpret_cast<const float2*>(x1 + (size_t)s * HID + f0);
        acc.x += w * v.x;
        acc.y += w * v.y;
    }
    float dv = dinv[d];
    float ws = dv * dv;
    float2 v = *reinterpret_cast<const float2*>(x1 + (size_t)d * HID + f0);
    acc.x += ws * v.x;
    acc.y += ws * v.y;
    *reinterpret_cast<float2*>(agg2 + (size_t)d * HID + f0) = acc;
}

// ---------- x2 = relu(agg2 @ W2 + b2)  (8 nodes/block, 32 lanes/node, float4) ----------
__global__ void __launch_bounds__(256) k_l2(const float* __restrict__ agg2,
                                            const float* __restrict__ W2,
                                            const float* __restrict__ b2,
                                            float* __restrict__ x2) {
    int g = threadIdx.x >> 5;
    int l = threadIdx.x & 31;
    int node = blockIdx.x * 8 + g;
    int h0 = l * 4;
    const float4* arow = reinterpret_cast<const float4*>(agg2 + (size_t)node * HID);
    float4 acc = *reinterpret_cast<const float4*>(b2 + h0);
    #pragma unroll 4
    for (int f4 = 0; f4 < 32; ++f4) {
        float4 a  = arow[f4];
        float4 w0 = *reinterpret_cast<const float4*>(W2 + (f4 * 4 + 0) * HID + h0);
        float4 w1 = *reinterpret_cast<const float4*>(W2 + (f4 * 4 + 1) * HID + h0);
        float4 w2 = *reinterpret_cast<const float4*>(W2 + (f4 * 4 + 2) * HID + h0);
        float4 w3 = *reinterpret_cast<const float4*>(W2 + (f4 * 4 + 3) * HID + h0);
        acc.x += a.x * w0.x + a.y * w1.x + a.z * w2.x + a.w * w3.x;
        acc.y += a.x * w0.y + a.y * w1.y + a.z * w2.y + a.w * w3.y;
        acc.z += a.x * w0.z + a.y * w1.z + a.z * w2.z + a.w * w3.z;
        acc.w += a.x * w0.w + a.y * w1.w + a.z * w2.w + a.w * w3.w;
    }
    float4 r;
    r.x = fmaxf(acc.x, 0.0f); r.y = fmaxf(acc.y, 0.0f);
    r.z = fmaxf(acc.z, 0.0f); r.w = fmaxf(acc.w, 0.0f);
    *reinterpret_cast<float4*>(x2 + (size_t)node * HID + h0) = r;
}

// ---------- fused fc1(+relu) + fc2 ----------
__global__ void __launch_bounds__(256) k_fc(const float* __restrict__ x2,
                                            const float* __restrict__ fc1w,
                                            const float* __restrict__ fc1b,
                                            const float* __restrict__ fc2w,
                                            const float* __restrict__ fc2b,
                                            float* __restrict__ out) {
    int g = threadIdx.x >> 5;
    int l = threadIdx.x & 31;
    int node = blockIdx.x * 8 + g;
    int h0 = l * 4;
    const float4* xrow = reinterpret_cast<const float4*>(x2 + (size_t)node * HID);
    float4 acc = *reinterpret_cast<const float4*>(fc1b + h0);
    #pragma unroll 4
    for (int f4 = 0; f4 < 32; ++f4) {
        float4 a  = xrow[f4];
        float4 w0 = *reinterpret_cast<const float4*>(fc1w + (f4 * 4 + 0) * HID + h0);
        float4 w1 = *reinterpret_cast<const float4*>(fc1w + (f4 * 4 + 1) * HID + h0);
        float4 w2 = *reinterpret_cast<const float4*>(fc1w + (f4 * 4 + 2) * HID + h0);
        float4 w3 = *reinterpret_cast<const float4*>(fc1w + (f4 * 4 + 3) * HID + h0);
        acc.x += a.x * w0.x + a.y * w1.x + a.z * w2.x + a.w * w3.x;
        acc.y += a.x * w0.y + a.y * w1.y + a.z * w2.y + a.w * w3.y;
        acc.z += a.x * w0.z + a.y * w1.z + a.z * w2.z + a.w * w3.z;
        acc.w += a.x * w0.w + a.y * w1.w + a.z * w2.w + a.w * w3.w;
    }
    acc.x = fmaxf(acc.x, 0.0f); acc.y = fmaxf(acc.y, 0.0f);
    acc.z = fmaxf(acc.z, 0.0f); acc.w = fmaxf(acc.w, 0.0f);
    float4 w = *reinterpret_cast<const float4*>(fc2w + h0);
    float p = acc.x * w.x + acc.y * w.y + acc.z * w.z + acc.w * w.w;
    #pragma unroll
    for (int m = 16; m >= 1; m >>= 1) p += __shfl_xor(p, m);
    if (l == 0) out[node] = p + fc2b[0];
}

extern "C" void kernel_launch(void* const* d_in, const int* in_sizes, int n_in,
                              void* d_out, int out_size, void* d_ws, size_t ws_size,
                              hipStream_t stream) {
    const float* obs  = (const float*)d_in[0];
    const int*   ei   = (const int*)d_in[1];
    const float* W1   = (const float*)d_in[2];
    const float* b1   = (const float*)d_in[3];
    const float* W2   = (const float*)d_in[4];
    const float* b2   = (const float*)d_in[5];
    const float* fc1w = (const float*)d_in[6];
    const float* fc1b = (const float*)d_in[7];
    const float* fc2w = (const float*)d_in[8];
    const float* fc2b = (const float*)d_in[9];
    float* out = (float*)d_out;

    char* base = (char*)d_ws;
    size_t off = 0;
    auto take = [&](size_t bytes) {
        char* p = base + off;
        off += (bytes + 255) & ~(size_t)255;
        return p;
    };
    int*   deg     = (int*)take((size_t)NGRAPH * 4);
    int*   rowptr  = (int*)take((size_t)NGRAPH * 4);
    int*   fill    = (int*)take((size_t)NGRAPH * 4);
    int*   sums    = (int*)take((size_t)NBLK * 4);
    float* dinv    = (float*)take((size_t)NGRAPH * 4);
    int*   csr_src = (int*)take((size_t)NEDGE * 4);
    float* csr_w   = (float*)take((size_t)NEDGE * 4);
    float* comb    = (float*)take((size_t)NGRAPH * 7 * 4);
    float* agg1    = (float*)take((size_t)NGRAPH * 7 * 4);
    float* x1      = (float*)take((size_t)NGRAPH * HID * 4);
    float* agg2    = (float*)take((size_t)NGRAPH * HID * 4);
    int*   flag    = (int*)take(256);

    k_detect<<<1, 64, 0, stream>>>(ei, flag);
    k_prep<<<(NGRAPH + 255) / 256, 256, 0, stream>>>(obs, comb, deg, fill);
    k_deg<<<(NEDGE + 255) / 256, 256, 0, stream>>>(ei, flag, deg);
    k_dinv<<<(NGRAPH + 255) / 256, 256, 0, stream>>>(deg, dinv);
    k_scan1<<<NBLK, SCAN_B, 0, stream>>>(deg, rowptr, sums);
    k_scan2<<<1, 256, 0, stream>>>(sums);
    k_scan3<<<NBLK, SCAN_B, 0, stream>>>(rowptr, sums);
    k_fill<<<(NEDGE + 255) / 256, 256, 0, stream>>>(ei, flag, dinv, rowptr, fill,
                                                    csr_src, csr_w);
    k_agg7<<<NGRAPH / 32, 256, 0, stream>>>(rowptr, deg, csr_src, csr_w, dinv,
                                            comb, agg1);
    k_l1<<<NGRAPH, 128, 0, stream>>>(agg1, W1, b1, x1);
    k_agg2<<<NGRAPH / 4, 256, 0, stream>>>(rowptr, deg, csr_src, csr_w, dinv,
                                           x1, agg2);
    k_l2<<<NGRAPH / 8, 256, 0, stream>>>(agg2, W2, b2, x1 /* reuse as x2 */);
    k_fc<<<NGRAPH / 8, 256, 0, stream>>>(x1, fc1w, fc1b, fc2w, fc2b, out);
}

// Round 6
// 614.063 us; speedup vs baseline: 6.6551x; 1.4865x over previous
//
#include <hip/hip_runtime.h>

#define NGRAPH 100000
#define NEDGE  1600000
#define HID    128
#define SCAN_B 512
#define NBLK   ((NGRAPH + SCAN_B - 1) / SCAN_B)   // 196
#define TILE   32                                  // nodes per k_mlp block

// ---------- dtype detection: int64 edge_index has all-zero odd 32-bit words ----------
__global__ void k_detect(const int* __restrict__ ei, int* __restrict__ flag) {
    int t = threadIdx.x;                       // 64 threads
    int v = ei[2 * t + 1];                     // odd words of src region
    unsigned long long b = __ballot(v != 0);
    if (t == 0) flag[0] = (b == 0ull) ? 1 : 0; // 1 => int64, 0 => int32
}

__device__ __forceinline__ int e_src(const int* ei, int is64, int e) {
    return is64 ? ei[2 * e] : ei[e];
}
__device__ __forceinline__ int e_dst(const int* ei, int is64, int e) {
    return is64 ? ei[2 * NEDGE + 2 * e] : ei[NEDGE + e];
}

// ---------- combined features [NGRAPH][7]; deg (edge-only) = 0; fill = 0 ----------
__global__ void k_prep(const float* __restrict__ obs,
                       float* __restrict__ comb, int* __restrict__ deg,
                       int* __restrict__ fill) {
    int i = blockIdx.x * blockDim.x + threadIdx.x;
    if (i >= NGRAPH) return;
    int n = i / 20, c = i % 20;
    const float* nf = obs + 3 + n * 4;
    const float* cf = obs + 3 + 20000 + c * 3;
    float* o = comb + i * 7;
    o[0] = nf[0]; o[1] = nf[1]; o[2] = nf[2]; o[3] = nf[3];
    o[4] = cf[0]; o[5] = cf[1]; o[6] = cf[2];
    deg[i] = 0;
    fill[i] = 0;
}

__global__ void k_deg(const int* __restrict__ ei, const int* __restrict__ flag,
                      int* __restrict__ deg) {
    int e = blockIdx.x * blockDim.x + threadIdx.x;
    if (e >= NEDGE) return;
    atomicAdd(&deg[e_dst(ei, flag[0], e)], 1);
}

__global__ void k_dinv(const int* __restrict__ deg, float* __restrict__ dinv) {
    int i = blockIdx.x * blockDim.x + threadIdx.x;
    if (i >= NGRAPH) return;
    dinv[i] = rsqrtf((float)(deg[i] + 1));     // +1: self loop
}

// ---------- exclusive scan of deg -> rowptr (3-kernel hierarchical) ----------
__global__ void __launch_bounds__(SCAN_B) k_scan1(const int* __restrict__ deg,
                                                  int* __restrict__ rowptr,
                                                  int* __restrict__ sums) {
    __shared__ int sh[SCAN_B];
    int t = threadIdx.x;
    int i = blockIdx.x * SCAN_B + t;
    int val = (i < NGRAPH) ? deg[i] : 0;
    sh[t] = val;
    __syncthreads();
    for (int o = 1; o < SCAN_B; o <<= 1) {
        int x = (t >= o) ? sh[t - o] : 0;
        __syncthreads();
        sh[t] += x;
        __syncthreads();
    }
    if (i < NGRAPH) rowptr[i] = sh[t] - val;          // exclusive within block
    if (t == SCAN_B - 1) sums[blockIdx.x] = sh[t];    // block total
}

__global__ void __launch_bounds__(256) k_scan2(int* __restrict__ sums) {
    __shared__ int sh[256];
    int t = threadIdx.x;
    int val = (t < NBLK) ? sums[t] : 0;
    sh[t] = val;
    __syncthreads();
    for (int o = 1; o < 256; o <<= 1) {
        int x = (t >= o) ? sh[t - o] : 0;
        __syncthreads();
        sh[t] += x;
        __syncthreads();
    }
    if (t < NBLK) sums[t] = sh[t] - val;              // exclusive block offsets
}

__global__ void __launch_bounds__(SCAN_B) k_scan3(int* __restrict__ rowptr,
                                                  const int* __restrict__ sums) {
    int i = blockIdx.x * SCAN_B + threadIdx.x;
    if (i < NGRAPH) rowptr[i] += sums[blockIdx.x];
}

// ---------- scatter edges into CSR slots ----------
__global__ void k_fill(const int* __restrict__ ei, const int* __restrict__ flag,
                       const float* __restrict__ dinv,
                       const int* __restrict__ rowptr, int* __restrict__ fill,
                       int* __restrict__ csr_src, float* __restrict__ csr_w) {
    int e = blockIdx.x * blockDim.x + threadIdx.x;
    if (e >= NEDGE) return;
    int is64 = flag[0];
    int s = e_src(ei, is64, e);
    int d = e_dst(ei, is64, e);
    int pos = rowptr[d] + atomicAdd(&fill[d], 1);
    csr_src[pos] = s;
    csr_w[pos] = dinv[s] * dinv[d];
}

// ---------- layer-1 agg over CSR: 8 lanes/node on 7-dim raw features ----------
__global__ void __launch_bounds__(256) k_agg7(const int* __restrict__ rowptr,
                                              const int* __restrict__ deg,
                                              const int* __restrict__ csr_src,
                                              const float* __restrict__ csr_w,
                                              const float* __restrict__ dinv,
                                              const float* __restrict__ comb,
                                              float* __restrict__ agg1) {
    int d = blockIdx.x * 32 + (threadIdx.x >> 3);
    int f = threadIdx.x & 7;
    if (f >= 7) return;
    int start = rowptr[d], n = deg[d];
    float acc = 0.0f;
    for (int j = 0; j < n; ++j) {
        int s = csr_src[start + j];
        float w = csr_w[start + j];
        acc += w * comb[s * 7 + f];
    }
    float dv = dinv[d];
    acc += dv * dv * comb[d * 7 + f];                 // self loop
    agg1[d * 7 + f] = acc;
}

// ---------- x1 = relu(agg1 @ W1 + b1) ----------
__global__ void __launch_bounds__(128) k_l1(const float* __restrict__ agg1,
                                            const float* __restrict__ W1,
                                            const float* __restrict__ b1,
                                            float* __restrict__ x1) {
    int i = blockIdx.x;
    int h = threadIdx.x;
    float a[7];
    #pragma unroll
    for (int f = 0; f < 7; ++f) a[f] = agg1[i * 7 + f];
    float acc = b1[h];
    #pragma unroll
    for (int f = 0; f < 7; ++f) acc += a[f] * W1[f * HID + h];
    x1[i * HID + h] = fmaxf(acc, 0.0f);
}

// ---------- layer-2 agg over CSR: 1 wave/node, lane holds 2 of 128 feats ----------
__global__ void __launch_bounds__(256) k_agg2(const int* __restrict__ rowptr,
                                              const int* __restrict__ deg,
                                              const int* __restrict__ csr_src,
                                              const float* __restrict__ csr_w,
                                              const float* __restrict__ dinv,
                                              const float* __restrict__ x1,
                                              float* __restrict__ agg2) {
    int wave = threadIdx.x >> 6;
    int lane = threadIdx.x & 63;
    int d = blockIdx.x * 4 + wave;
    int f0 = lane * 2;
    int start = rowptr[d], n = deg[d];
    float2 acc = {0.0f, 0.0f};
    for (int j = 0; j < n; ++j) {
        int s = csr_src[start + j];        // same addr across wave -> broadcast
        float w = csr_w[start + j];
        float2 v = *reinterpret_cast<const float2*>(x1 + (size_t)s * HID + f0);
        acc.x += w * v.x;
        acc.y += w * v.y;
    }
    float dv = dinv[d];
    float ws = dv * dv;
    float2 v = *reinterpret_cast<const float2*>(x1 + (size_t)d * HID + f0);
    acc.x += ws * v.x;
    acc.y += ws * v.y;
    *reinterpret_cast<float2*>(agg2 + (size_t)d * HID + f0) = acc;
}

// ---------- fused dense tail: x2=relu(agg2@W2+b2); x3=relu(x2@fc1+b); out=x3@fc2+b ----
// Block = 256 threads = (32 out-groups) x (8 node-groups); each thread: 4 nodes x 4 feats.
// Per K-chunk of 4: 8 float4 loads -> 64 FMAs (8:1 FMA:load vs 3.2:1 in old k_l2).
__device__ __forceinline__ void fma4(float4& acc, const float4 a,
                                     const float4 w0, const float4 w1,
                                     const float4 w2, const float4 w3) {
    acc.x += a.x * w0.x + a.y * w1.x + a.z * w2.x + a.w * w3.x;
    acc.y += a.x * w0.y + a.y * w1.y + a.z * w2.y + a.w * w3.y;
    acc.z += a.x * w0.z + a.y * w1.z + a.z * w2.z + a.w * w3.z;
    acc.w += a.x * w0.w + a.y * w1.w + a.z * w2.w + a.w * w3.w;
}
__device__ __forceinline__ float4 relu4(float4 v) {
    float4 r;
    r.x = fmaxf(v.x, 0.0f); r.y = fmaxf(v.y, 0.0f);
    r.z = fmaxf(v.z, 0.0f); r.w = fmaxf(v.w, 0.0f);
    return r;
}

__global__ void __launch_bounds__(256) k_mlp(const float* __restrict__ agg2,
                                             const float* __restrict__ W2,
                                             const float* __restrict__ b2,
                                             const float* __restrict__ fc1w,
                                             const float* __restrict__ fc1b,
                                             const float* __restrict__ fc2w,
                                             const float* __restrict__ fc2b,
                                             float* __restrict__ out) {
    __shared__ float xs[TILE][HID + 4];   // row stride 132 floats = 528 B (16B-aligned)
    const int tx = threadIdx.x & 31;      // output group: h0 = tx*4
    const int ty = threadIdx.x >> 5;      // node group: nodes ty*4 .. ty*4+3
    const int n0 = blockIdx.x * TILE;
    const int h0 = tx * 4;
    const float* arow = agg2 + (size_t)(n0 + ty * 4) * HID;

    // ---- phase A: x2 tile = relu(agg2 @ W2 + b2) ----
    float4 bias = *reinterpret_cast<const float4*>(b2 + h0);
    float4 c0 = bias, c1 = bias, c2 = bias, c3 = bias;
    for (int k = 0; k < HID; k += 4) {
        float4 a0 = *reinterpret_cast<const float4*>(arow + 0 * HID + k);
        float4 a1 = *reinterpret_cast<const float4*>(arow + 1 * HID + k);
        float4 a2 = *reinterpret_cast<const float4*>(arow + 2 * HID + k);
        float4 a3 = *reinterpret_cast<const float4*>(arow + 3 * HID + k);
        float4 w0 = *reinterpret_cast<const float4*>(W2 + (k + 0) * HID + h0);
        float4 w1 = *reinterpret_cast<const float4*>(W2 + (k + 1) * HID + h0);
        float4 w2 = *reinterpret_cast<const float4*>(W2 + (k + 2) * HID + h0);
        float4 w3 = *reinterpret_cast<const float4*>(W2 + (k + 3) * HID + h0);
        fma4(c0, a0, w0, w1, w2, w3);
        fma4(c1, a1, w0, w1, w2, w3);
        fma4(c2, a2, w0, w1, w2, w3);
        fma4(c3, a3, w0, w1, w2, w3);
    }
    *reinterpret_cast<float4*>(&xs[ty * 4 + 0][h0]) = relu4(c0);
    *reinterpret_cast<float4*>(&xs[ty * 4 + 1][h0]) = relu4(c1);
    *reinterpret_cast<float4*>(&xs[ty * 4 + 2][h0]) = relu4(c2);
    *reinterpret_cast<float4*>(&xs[ty * 4 + 3][h0]) = relu4(c3);
    __syncthreads();

    // ---- phase B: x3 = relu(x2 @ fc1w + fc1b) ----
    float4 bias1 = *reinterpret_cast<const float4*>(fc1b + h0);
    float4 d0 = bias1, d1 = bias1, d2 = bias1, d3 = bias1;
    for (int k = 0; k < HID; k += 4) {
        float4 a0 = *reinterpret_cast<const float4*>(&xs[ty * 4 + 0][k]);
        float4 a1 = *reinterpret_cast<const float4*>(&xs[ty * 4 + 1][k]);
        float4 a2 = *reinterpret_cast<const float4*>(&xs[ty * 4 + 2][k]);
        float4 a3 = *reinterpret_cast<const float4*>(&xs[ty * 4 + 3][k]);
        float4 w0 = *reinterpret_cast<const float4*>(fc1w + (k + 0) * HID + h0);
        float4 w1 = *reinterpret_cast<const float4*>(fc1w + (k + 1) * HID + h0);
        float4 w2 = *reinterpret_cast<const float4*>(fc1w + (k + 2) * HID + h0);
        float4 w3 = *reinterpret_cast<const float4*>(fc1w + (k + 3) * HID + h0);
        fma4(d0, a0, w0, w1, w2, w3);
        fma4(d1, a1, w0, w1, w2, w3);
        fma4(d2, a2, w0, w1, w2, w3);
        fma4(d3, a3, w0, w1, w2, w3);
    }
    d0 = relu4(d0); d1 = relu4(d1); d2 = relu4(d2); d3 = relu4(d3);

    // ---- phase C: out = x3 @ fc2w + fc2b (reduce over h across the 32 tx lanes) ----
    float4 wq = *reinterpret_cast<const float4*>(fc2w + h0);
    float p0 = d0.x * wq.x + d0.y * wq.y + d0.z * wq.z + d0.w * wq.w;
    float p1 = d1.x * wq.x + d1.y * wq.y + d1.z * wq.z + d1.w * wq.w;
    float p2 = d2.x * wq.x + d2.y * wq.y + d2.z * wq.z + d2.w * wq.w;
    float p3 = d3.x * wq.x + d3.y * wq.y + d3.z * wq.z + d3.w * wq.w;
    #pragma unroll
    for (int m = 1; m < 32; m <<= 1) {     // xor-mask < 32 stays within the tx half
        p0 += __shfl_xor(p0, m);
        p1 += __shfl_xor(p1, m);
        p2 += __shfl_xor(p2, m);
        p3 += __shfl_xor(p3, m);
    }
    if (tx == 0) {
        float bq = fc2b[0];
        int nb = n0 + ty * 4;
        out[nb + 0] = p0 + bq;
        out[nb + 1] = p1 + bq;
        out[nb + 2] = p2 + bq;
        out[nb + 3] = p3 + bq;
    }
}

extern "C" void kernel_launch(void* const* d_in, const int* in_sizes, int n_in,
                              void* d_out, int out_size, void* d_ws, size_t ws_size,
                              hipStream_t stream) {
    const float* obs  = (const float*)d_in[0];
    const int*   ei   = (const int*)d_in[1];
    const float* W1   = (const float*)d_in[2];
    const float* b1   = (const float*)d_in[3];
    const float* W2   = (const float*)d_in[4];
    const float* b2   = (const float*)d_in[5];
    const float* fc1w = (const float*)d_in[6];
    const float* fc1b = (const float*)d_in[7];
    const float* fc2w = (const float*)d_in[8];
    const float* fc2b = (const float*)d_in[9];
    float* out = (float*)d_out;

    char* base = (char*)d_ws;
    size_t off = 0;
    auto take = [&](size_t bytes) {
        char* p = base + off;
        off += (bytes + 255) & ~(size_t)255;
        return p;
    };
    int*   deg     = (int*)take((size_t)NGRAPH * 4);
    int*   rowptr  = (int*)take((size_t)NGRAPH * 4);
    int*   fill    = (int*)take((size_t)NGRAPH * 4);
    int*   sums    = (int*)take((size_t)NBLK * 4);
    float* dinv    = (float*)take((size_t)NGRAPH * 4);
    int*   csr_src = (int*)take((size_t)NEDGE * 4);
    float* csr_w   = (float*)take((size_t)NEDGE * 4);
    float* comb    = (float*)take((size_t)NGRAPH * 7 * 4);
    float* agg1    = (float*)take((size_t)NGRAPH * 7 * 4);
    float* x1      = (float*)take((size_t)NGRAPH * HID * 4);
    float* agg2    = (float*)take((size_t)NGRAPH * HID * 4);
    int*   flag    = (int*)take(256);

    k_detect<<<1, 64, 0, stream>>>(ei, flag);
    k_prep<<<(NGRAPH + 255) / 256, 256, 0, stream>>>(obs, comb, deg, fill);
    k_deg<<<(NEDGE + 255) / 256, 256, 0, stream>>>(ei, flag, deg);
    k_dinv<<<(NGRAPH + 255) / 256, 256, 0, stream>>>(deg, dinv);
    k_scan1<<<NBLK, SCAN_B, 0, stream>>>(deg, rowptr, sums);
    k_scan2<<<1, 256, 0, stream>>>(sums);
    k_scan3<<<NBLK, SCAN_B, 0, stream>>>(rowptr, sums);
    k_fill<<<(NEDGE + 255) / 256, 256, 0, stream>>>(ei, flag, dinv, rowptr, fill,
                                                    csr_src, csr_w);
    k_agg7<<<NGRAPH / 32, 256, 0, stream>>>(rowptr, deg, csr_src, csr_w, dinv,
                                            comb, agg1);
    k_l1<<<NGRAPH, 128, 0, stream>>>(agg1, W1, b1, x1);
    k_agg2<<<NGRAPH / 4, 256, 0, stream>>>(rowptr, deg, csr_src, csr_w, dinv,
                                           x1, agg2);
    k_mlp<<<NGRAPH / TILE, 256, 0, stream>>>(agg2, W2, b2, fc1w, fc1b,
                                             fc2w, fc2b, out);
}